// Round 13
// baseline (446.815 us; speedup 1.0000x reference)
//
#include <hip/hip_runtime.h>
#include <hip/hip_bf16.h>
#include <stdint.h>

// Problem constants
#define KD 2304    // K = C*3*3
#define LD 3136    // L = 56*56
#define ND 256     // output channels
#define MD 25088   // B*L
#define CD 256     // input channels
#define PITCH 64   // padded row pitch (floats)
#define PROWS 58
#define PLANE (PROWS * PITCH)

typedef __bf16 bf16x8 __attribute__((ext_vector_type(8)));
typedef float f32x4 __attribute__((ext_vector_type(4)));
typedef float f32x4u __attribute__((ext_vector_type(4), aligned(4)));

__device__ __forceinline__ void gload_lds16(const void* g, void* l) {
  __builtin_amdgcn_global_load_lds(
      (const __attribute__((address_space(1))) unsigned int*)g,
      (__attribute__((address_space(3))) unsigned int*)l, 16, 0, 0);
}

// ---------------- Phase -1: zero-pad x into [B*C][58][PITCH=64] ----------------
__global__ __launch_bounds__(256) void pad_kernel(
    const float* __restrict__ x, float* __restrict__ xpad) {
  const int plane = blockIdx.x;
  const float* src = x + (size_t)plane * LD;
  float* dst = xpad + (size_t)plane * PLANE;
  const int cc4 = (threadIdx.x & 15) * 4;
  const int r0 = threadIdx.x >> 4;
#pragma unroll
  for (int p = 0; p < 4; ++p) {
    const int r = r0 + p * 16;
    if (r >= PROWS) continue;
    f32x4 o = {0.f, 0.f, 0.f, 0.f};
    if (r >= 1 && r <= 56) {
      const float* srow = src + (r - 1) * 56;
      if (cc4 == 0) {
        f32x4u v = *(const f32x4u*)(srow);
        o[1] = v[0]; o[2] = v[1]; o[3] = v[2];
      } else if (cc4 <= 52) {
        o = *(const f32x4u*)(srow + cc4 - 1);
      } else if (cc4 == 56) {
        f32x4u v = *(const f32x4u*)(srow + 52);
        o[0] = v[3];
      }
    }
    *(f32x4*)(dst + r * PITCH + cc4) = o;
  }
}

// ---------------- Phase 0: weight fake-quant -> wqT [N][K] bf16 ----------------
__global__ __launch_bounds__(256) void quant_w_kernel(
    const float* __restrict__ w, __hip_bfloat16* __restrict__ wqT) {
  const int gk = blockIdx.x % 72;
  const int gn = blockIdx.x / 72;
  const int n = gn * 32 + (threadIdx.x >> 3);
  const int k = gk * 32 + (threadIdx.x & 7) * 4;
  const float4 v = *(const float4*)(w + (size_t)n * KD + k);
  float a = fmaxf(fmaxf(fabsf(v.x), fabsf(v.y)), fmaxf(fabsf(v.z), fabsf(v.w)));
#pragma unroll
  for (int m = 1; m <= 32; m <<= 1) a = fmaxf(a, __shfl_xor(a, m, 64));
  __shared__ float red[4];
  if ((threadIdx.x & 63) == 0) red[threadIdx.x >> 6] = a;
  __syncthreads();
  const float mx = fmaxf(fmaxf(red[0], red[1]), fmaxf(red[2], red[3]));
  const float r63 = (mx == 0.f) ? 0.f : 63.f / mx;
  const float scale = mx * (1.f / 63.f);
  ushort4 o;
  o.x = __builtin_bit_cast(unsigned short, __float2bfloat16(rintf(v.x * r63) * scale));
  o.y = __builtin_bit_cast(unsigned short, __float2bfloat16(rintf(v.y * r63) * scale));
  o.z = __builtin_bit_cast(unsigned short, __float2bfloat16(rintf(v.z * r63) * scale));
  o.w = __builtin_bit_cast(unsigned short, __float2bfloat16(rintf(v.w * r63) * scale));
  *(ushort4*)((unsigned short*)wqT + (size_t)n * KD + k) = o;
}

// ---- phase-exact window load for one 32-k granule (11-12 f32x4 loads) ----
template <int KP0>
__device__ __forceinline__ void qloadT(const float* __restrict__ pb, int p0, int c0,
                                       f32x4u (&win)[5][3]) {
  constexpr int NCH = (KP0 + 31) / 9 + 1;   // 4 or 5 channels
#pragma unroll
  for (int dc = 0; dc < 5; ++dc) {
    if (dc >= NCH) continue;
    const int tlo = (dc == 0) ? KP0 : 0;
    const int thi = (dc == NCH - 1) ? (KP0 + 31 - 9 * (NCH - 1)) : 8;
    const int cdc = (c0 + dc > 255) ? 255 : c0 + dc;   // clamp for tail dummies
    const float* cp = pb + p0 + cdc * PLANE;
#pragma unroll
    for (int di = 0; di < 3; ++di) {
      if (di >= tlo / 3 && di <= thi / 3)
        win[dc][di] = *(const f32x4u*)(cp + di * PITCH);
    }
  }
}

// win element for granule-tap index i (channel-relative to c0 = kbase/9)
#define WIN(i) (win[(i) / 9][((i) % 9) / 3][(i) % 3])

// ---- quantize this lane's 8-element k-slice of its row's 32-k granule ----
// lane row = l&15, slice hi = l>>4. Row-granule max via 2x shfl_xor.
// Result = the MFMA operand fragment (8 bf16 in 4 dwords) directly.
template <int KP0>
__device__ __forceinline__ bf16x8 quant_gran(const f32x4u (&win)[5][3],
                                             bool h1, bool h2) {
  float v[8];
#pragma unroll
  for (int e = 0; e < 8; ++e) {
    const float s0 = WIN(KP0 + e);
    const float s1 = WIN(KP0 + 8 + e);
    const float s2 = WIN(KP0 + 16 + e);
    const float s3 = WIN(KP0 + 24 + e);
    const float a = h1 ? s1 : s0;
    const float bb = h1 ? s3 : s2;
    v[e] = h2 ? bb : a;
  }
  float m = fmaxf(fmaxf(fmaxf(__builtin_fabsf(v[0]), __builtin_fabsf(v[1])),
                        fmaxf(__builtin_fabsf(v[2]), __builtin_fabsf(v[3]))),
                  fmaxf(fmaxf(__builtin_fabsf(v[4]), __builtin_fabsf(v[5])),
                        fmaxf(__builtin_fabsf(v[6]), __builtin_fabsf(v[7]))));
  m = fmaxf(m, __shfl_xor(m, 16));
  m = fmaxf(m, __shfl_xor(m, 32));
  float r63 = 63.f * __builtin_amdgcn_rcpf(m);
  r63 = (m == 0.f) ? 0.f : r63;
  const float scale = m * (1.f / 63.f);
  union { unsigned u[4]; bf16x8 f; } cv;
#pragma unroll
  for (int t = 0; t < 4; ++t) {
    const float a = rintf(v[2 * t] * r63) * scale;
    const float b = rintf(v[2 * t + 1] * r63) * scale;
    asm("v_cvt_pk_bf16_f32 %0, %1, %2" : "=v"(cv.u[t]) : "v"(a), "v"(b));
  }
  return cv.f;
}

// ---- stage 128n x 64k wqT tile (16KB) via global_load_lds, swizzled source ----
// 16 chunks of 1KB (8 rows x 128B); 4 per wave -> vmcnt contribution = 4/wave.
__device__ __forceinline__ void stage_ns(const unsigned short* __restrict__ wsrc,
                                         int k0, int lane, int w,
                                         char* __restrict__ Ns) {
#pragma unroll
  for (int sg = 0; sg < 4; ++sg) {
    const int c = w * 4 + sg;              // 0..15
    const int row = c * 8 + (lane >> 3);   // 0..127
    const int u = (lane & 7) ^ (row & 7);
    gload_lds16(wsrc + (size_t)row * KD + k0 + u * 8, Ns + c * 1024 + lane * 16);
  }
}

// ---- one span = 2 granules (64 k). Barrier-free inside; 1 barrier at end. ----
template <int P>
__device__ __forceinline__ void span_body(
    const float* __restrict__ pb, int p0, int sp, f32x4u (&win)[5][3],
    f32x4 (&acc)[8], const char* __restrict__ NsR, char* __restrict__ NsW,
    const unsigned short* __restrict__ wsrc, bool h1, bool h2,
    int lane, int w, int lq, int hv) {
  constexpr int PB = (P + 5) % 9;
  constexpr int PA2 = (P + 1) % 9;
  // ---- granule A (k parity 0): win(A) ready after vmcnt(0) ----
  asm volatile("s_waitcnt vmcnt(0)" ::: "memory");
  __builtin_amdgcn_sched_barrier(0);
  const bf16x8 afA = quant_gran<P>(win, h1, h2);
  qloadT<PB>(pb, p0, (64 * sp + 32) / 9, win);      // prefetch win(B)
  __builtin_amdgcn_s_setprio(1);
#pragma unroll
  for (int jj = 0; jj < 8; ++jj) {
    const unsigned r = (unsigned)(jj * 16 + lq);
    const bf16x8 bfr = *(const bf16x8*)(NsR + r * 128u + (unsigned)((hv ^ (r & 7)) * 16));
    acc[jj] = __builtin_amdgcn_mfma_f32_16x16x32_bf16(bfr, afA, acc[jj], 0, 0, 0);
  }
  __builtin_amdgcn_s_setprio(0);
  // ---- stage next span's weight tile (async; overlaps granule B) ----
  {
    const int kst = ((sp + 1) < 36 ? (sp + 1) : 35) * 64;   // dummy on last
    stage_ns(wsrc, kst, lane, w, NsW);
  }
  // ---- granule B (k parity 1): vmcnt(4) leaves the 4 stage loads in flight ----
  asm volatile("s_waitcnt vmcnt(4)" ::: "memory");
  __builtin_amdgcn_sched_barrier(0);
  const bf16x8 afB = quant_gran<PB>(win, h1, h2);
  qloadT<PA2>(pb, p0, (64 * sp + 64) / 9, win);     // prefetch win(A') next span
  __builtin_amdgcn_s_setprio(1);
#pragma unroll
  for (int jj = 0; jj < 8; ++jj) {
    const unsigned r = (unsigned)(jj * 16 + lq);
    const bf16x8 bfr = *(const bf16x8*)(NsR + r * 128u + (unsigned)(((4 + hv) ^ (r & 7)) * 16));
    acc[jj] = __builtin_amdgcn_mfma_f32_16x16x32_bf16(bfr, afB, acc[jj], 0, 0, 0);
  }
  __builtin_amdgcn_s_setprio(0);
  // drain stage(sp+1) (4 oldest of <=16 pending), publish, barrier
  asm volatile("s_waitcnt vmcnt(11) lgkmcnt(0)\n\ts_barrier" ::: "memory");
  __builtin_amdgcn_sched_barrier(0);
}

// ---------------- Fused: in-register quant fragments, 1 barrier / 2 granules ----
// 256 thr (4 waves x 16 m-rows), BM=64, BN=128, grid 784 (3.06/CU, balanced).
// LDS = Ns dbuf 2x16KB = 32KB. No As tile: each wave's quantized granule IS its
// MFMA operand (lane = row l&15, k-slice = l>>4; row-max via 2 shfl_xor).
__global__ __launch_bounds__(256, 3) void fused_gemm_kernel(
    const float* __restrict__ xpad, const __hip_bfloat16* __restrict__ wqT,
    const float* __restrict__ bias, float* __restrict__ out) {
  __shared__ char Ns[2][16384];
  const int tid = threadIdx.x;
  const int lane = tid & 63;
  const int w = __builtin_amdgcn_readfirstlane(tid >> 6);   // 0..3

  const int bid = blockIdx.x;                      // 0..783
  const int swz = (bid & 7) * 98 + (bid >> 3);     // XCD swizzle (784 % 8 == 0)
  const int mt = swz >> 1;                         // 0..391
  const int nt = swz & 1;
  const int m0 = mt * 64;
  const int n1 = nt * 128;

  const int lq = lane & 15, hv = lane >> 4;
  const bool h1 = (hv & 1) != 0, h2 = (hv & 2) != 0;

  // this lane's m-row (wave w owns rows m0+16w .. +15)
  const int b = m0 / LD;                           // uniform (3136 % 64 == 0)
  const int gm = m0 + w * 16 + lq;
  const int l = gm - b * LD;
  const int i = l / 56;
  const int j = l - i * 56;
  const float* pb = xpad + (size_t)b * CD * PLANE;
  const int p0 = i * PITCH + j;

  const unsigned short* wsrc = (const unsigned short*)wqT + (size_t)n1 * KD;

  f32x4 acc[8] = {};
  f32x4u win[5][3];

  // ---- prologue: stage(0) + win for granule 0; drain; barrier ----
  stage_ns(wsrc, 0, lane, w, Ns[0]);
  qloadT<0>(pb, p0, 0, win);
  asm volatile("s_waitcnt vmcnt(0) lgkmcnt(0)\n\ts_barrier" ::: "memory");
  __builtin_amdgcn_sched_barrier(0);

  // phase of granule A at span sp: (64*sp)%9 = sp%9 (64%9==1)
  int ph = 0;
  for (int sp = 0; sp < 36; ++sp) {
    const char* NsR = Ns[sp & 1];
    char* NsW = Ns[(sp + 1) & 1];
    switch (ph) {
      case 0: span_body<0>(pb, p0, sp, win, acc, NsR, NsW, wsrc, h1, h2, lane, w, lq, hv); break;
      case 1: span_body<1>(pb, p0, sp, win, acc, NsR, NsW, wsrc, h1, h2, lane, w, lq, hv); break;
      case 2: span_body<2>(pb, p0, sp, win, acc, NsR, NsW, wsrc, h1, h2, lane, w, lq, hv); break;
      case 3: span_body<3>(pb, p0, sp, win, acc, NsR, NsW, wsrc, h1, h2, lane, w, lq, hv); break;
      case 4: span_body<4>(pb, p0, sp, win, acc, NsR, NsW, wsrc, h1, h2, lane, w, lq, hv); break;
      case 5: span_body<5>(pb, p0, sp, win, acc, NsR, NsW, wsrc, h1, h2, lane, w, lq, hv); break;
      case 6: span_body<6>(pb, p0, sp, win, acc, NsR, NsW, wsrc, h1, h2, lane, w, lq, hv); break;
      case 7: span_body<7>(pb, p0, sp, win, acc, NsR, NsW, wsrc, h1, h2, lane, w, lq, hv); break;
      default: span_body<8>(pb, p0, sp, win, acc, NsR, NsW, wsrc, h1, h2, lane, w, lq, hv); break;
    }
    ph += 1; if (ph == 9) ph = 0;
  }
  asm volatile("s_waitcnt vmcnt(0)" ::: "memory");  // drain tail dummy loads

  // ---- Epilogue: D row = n = n1 + 16*jj + hv*4 + comp, col = m (coalesced) ----
  const int ll = gm - b * LD;
#pragma unroll
  for (int jj = 0; jj < 8; ++jj) {
    const int nb = n1 + jj * 16 + hv * 4;
    const float4 b4 = *(const float4*)&bias[nb];
    float* op = out + ((size_t)b * ND + nb) * LD + ll;
    op[0]      = acc[jj].x + b4.x;
    op[LD]     = acc[jj].y + b4.y;
    op[2 * LD] = acc[jj].z + b4.z;
    op[3 * LD] = acc[jj].w + b4.w;
  }
}

extern "C" void kernel_launch(void* const* d_in, const int* in_sizes, int n_in,
                              void* d_out, int out_size, void* d_ws, size_t ws_size,
                              hipStream_t stream) {
  const float* x = (const float*)d_in[0];
  const float* wgt = (const float*)d_in[1];
  const float* bias = (const float*)d_in[2];
  float* out = (float*)d_out;

  float* xpad = (float*)d_ws;                         // 30,408,704 B
  __hip_bfloat16* wqT = (__hip_bfloat16*)((char*)d_ws + 30408704);  // 1,179,648 B

  pad_kernel<<<8 * CD, 256, 0, stream>>>(x, xpad);
  quant_w_kernel<<<576, 256, 0, stream>>>(wgt, wqT);
  fused_gemm_kernel<<<784, 256, 0, stream>>>(xpad, wqT, bias, out);
}

// Round 14
// 70.274 us; speedup vs baseline: 6.3582x; 6.3582x over previous
//
#include <hip/hip_runtime.h>
#include <hip/hip_bf16.h>
#include <stdint.h>

// Problem constants
#define KD 2304    // K = C*3*3
#define LD 3136    // L = 56*56
#define ND 256     // output channels
#define MD 25088   // B*L
#define CD 256     // input channels
#define PITCH 64   // padded row pitch (floats)
#define PROWS 58
#define PLANE (PROWS * PITCH)

typedef __bf16 bf16x8 __attribute__((ext_vector_type(8)));
typedef float f32x4 __attribute__((ext_vector_type(4)));
typedef float f32x4u __attribute__((ext_vector_type(4), aligned(4)));

__device__ __forceinline__ void gload_lds16(const void* g, void* l) {
  __builtin_amdgcn_global_load_lds(
      (const __attribute__((address_space(1))) unsigned int*)g,
      (__attribute__((address_space(3))) unsigned int*)l, 16, 0, 0);
}

// ---------- prep: pad x into [B*C][58][64] (bid<2048) + weight quant (else) ----------
__global__ __launch_bounds__(256) void prep_kernel(
    const float* __restrict__ x, float* __restrict__ xpad,
    const float* __restrict__ w, __hip_bfloat16* __restrict__ wqT) {
  if (blockIdx.x < 2048) {
    const int plane = blockIdx.x;
    const float* src = x + (size_t)plane * LD;
    float* dst = xpad + (size_t)plane * PLANE;
    const int cc4 = (threadIdx.x & 15) * 4;
    const int r0 = threadIdx.x >> 4;
#pragma unroll
    for (int p = 0; p < 4; ++p) {
      const int r = r0 + p * 16;
      if (r >= PROWS) continue;
      f32x4 o = {0.f, 0.f, 0.f, 0.f};
      if (r >= 1 && r <= 56) {
        const float* srow = src + (r - 1) * 56;
        if (cc4 == 0) {
          f32x4u v = *(const f32x4u*)(srow);
          o[1] = v[0]; o[2] = v[1]; o[3] = v[2];
        } else if (cc4 <= 52) {
          o = *(const f32x4u*)(srow + cc4 - 1);
        } else if (cc4 == 56) {
          f32x4u v = *(const f32x4u*)(srow + 52);
          o[0] = v[3];
        }
      }
      *(f32x4*)(dst + r * PITCH + cc4) = o;
    }
  } else {
    const int wb = blockIdx.x - 2048;            // 0..575
    const int gk = wb % 72;
    const int gn = wb / 72;
    const int n = gn * 32 + (threadIdx.x >> 3);
    const int k = gk * 32 + (threadIdx.x & 7) * 4;
    const float4 v = *(const float4*)(w + (size_t)n * KD + k);
    float a = fmaxf(fmaxf(fabsf(v.x), fabsf(v.y)), fmaxf(fabsf(v.z), fabsf(v.w)));
#pragma unroll
    for (int m = 1; m <= 32; m <<= 1) a = fmaxf(a, __shfl_xor(a, m, 64));
    __shared__ float red[4];
    if ((threadIdx.x & 63) == 0) red[threadIdx.x >> 6] = a;
    __syncthreads();
    const float mx = fmaxf(fmaxf(red[0], red[1]), fmaxf(red[2], red[3]));
    const float r63 = (mx == 0.f) ? 0.f : 63.f / mx;
    const float scale = mx * (1.f / 63.f);
    ushort4 o;
    o.x = __builtin_bit_cast(unsigned short, __float2bfloat16(rintf(v.x * r63) * scale));
    o.y = __builtin_bit_cast(unsigned short, __float2bfloat16(rintf(v.y * r63) * scale));
    o.z = __builtin_bit_cast(unsigned short, __float2bfloat16(rintf(v.z * r63) * scale));
    o.w = __builtin_bit_cast(unsigned short, __float2bfloat16(rintf(v.w * r63) * scale));
    *(ushort4*)((unsigned short*)wqT + (size_t)n * KD + k) = o;
  }
}

// ---- UNIFORM window prefetch: 5 channels x 3 rows = 15 loads (vmcnt-constant) ----
__device__ __forceinline__ void qload_u(const float* __restrict__ pb, int p0,
                                        int c0, f32x4u (&win)[5][3]) {
#pragma unroll
  for (int dc = 0; dc < 5; ++dc) {
    const int cdc = (c0 + dc > 255) ? 255 : c0 + dc;
    const float* cp = pb + p0 + cdc * PLANE;
#pragma unroll
    for (int di = 0; di < 3; ++di)
      win[dc][di] = *(const f32x4u*)(cp + di * PITCH);
  }
}

// ---- finish quant -> swizzled As half-tile write (128B rows, 8x16B units) ----
// unit u of row r holds logical unit u^(r&7); row = lane.
template <int KP0>
__device__ __forceinline__ void qfinishT(const f32x4u (&win)[5][3],
                                         char* __restrict__ as_base,
                                         int lane, unsigned cbase) {
  float v[32];
#pragma unroll
  for (int t = 0; t < 32; ++t) {
    const int idx = KP0 + t;
    v[t] = win[idx / 9][(idx % 9) / 3][(idx % 9) % 3];
  }
  float m16[16];
#pragma unroll
  for (int t = 0; t < 16; ++t)
    m16[t] = fmaxf(__builtin_fabsf(v[2 * t]), __builtin_fabsf(v[2 * t + 1]));
#pragma unroll
  for (int t = 0; t < 8; ++t) m16[t] = fmaxf(m16[t], m16[t + 8]);
#pragma unroll
  for (int t = 0; t < 4; ++t) m16[t] = fmaxf(m16[t], m16[t + 4]);
  const float mx = fmaxf(fmaxf(m16[0], m16[1]), fmaxf(m16[2], m16[3]));
  float r63 = 63.f * __builtin_amdgcn_rcpf(mx);
  r63 = (mx == 0.f) ? 0.f : r63;
  const float scale = mx * (1.f / 63.f);
  unsigned pk[16];
#pragma unroll
  for (int t = 0; t < 16; ++t) {
    const float a = rintf(v[2 * t] * r63) * scale;
    const float b = rintf(v[2 * t + 1] * r63) * scale;
    unsigned d;
    asm("v_cvt_pk_bf16_f32 %0, %1, %2" : "=v"(d) : "v"(a), "v"(b));
    pk[t] = d;
  }
  char* row = as_base + lane * 128;
  const unsigned swz = (unsigned)((lane & 7) << 4);
#pragma unroll
  for (int s = 0; s < 4; ++s) {
    uint4 o = {pk[4 * s], pk[4 * s + 1], pk[4 * s + 2], pk[4 * s + 3]};
    *(uint4*)(row + ((cbase + (unsigned)(s * 16)) ^ swz)) = o;
  }
}

#define SW_FIN(PH, DST, CB)                                                   \
  switch (PH) {                                                               \
    case 0: qfinishT<0>(win, DST, lane, CB); break;                           \
    case 1: qfinishT<1>(win, DST, lane, CB); break;                           \
    case 2: qfinishT<2>(win, DST, lane, CB); break;                           \
    case 3: qfinishT<3>(win, DST, lane, CB); break;                           \
    case 4: qfinishT<4>(win, DST, lane, CB); break;                           \
    case 5: qfinishT<5>(win, DST, lane, CB); break;                           \
    case 6: qfinishT<6>(win, DST, lane, CB); break;                           \
    case 7: qfinishT<7>(win, DST, lane, CB); break;                           \
    default: qfinishT<8>(win, DST, lane, CB); break;                          \
  }

// ---- stage one 256n x 64k wqT half-tile (32KB, 128B rows) — 8 chunks/wave ----
__device__ __forceinline__ void stage_ns(const unsigned short* __restrict__ wsrc,
                                         int k0, int lane, int w,
                                         char* __restrict__ NsH) {
#pragma unroll
  for (int sg = 0; sg < 8; ++sg) {
    const int c = w * 8 + sg;              // 0..31, 1KB chunk = 8 rows x 128B
    const int row = c * 8 + (lane >> 3);   // 0..255
    const int u = (lane & 7) ^ (row & 7);
    gload_lds16(wsrc + (size_t)row * KD + k0 + u * 8, NsH + c * 1024 + lane * 16);
  }
}

// ---- MFMA: 4 waves, wave tile 64n x 64m, BK=128 over 2 half-tiles ----
__device__ __forceinline__ void mfma_phase(
    const char* __restrict__ As0, const char* __restrict__ As1,
    const char* __restrict__ Ns0, const char* __restrict__ Ns1,
    f32x4 (&acc)[4][4], int w, int lq, int hv) {
#pragma unroll
  for (int kk = 0; kk < 4; ++kk) {
    const char* NsH = (kk < 2) ? Ns0 : Ns1;
    const char* AsH = (kk < 2) ? As0 : As1;
    const int kl = kk & 1;
    bf16x8 af[4], bf[4];
#pragma unroll
    for (int i = 0; i < 4; ++i) {
      const unsigned rn = (unsigned)(w * 64 + i * 16 + lq);
      const unsigned u = (unsigned)((kl * 4 + hv) ^ (rn & 7));
      af[i] = *(const bf16x8*)(NsH + rn * 128u + u * 16u);
    }
#pragma unroll
    for (int j = 0; j < 4; ++j) {
      const unsigned rm = (unsigned)(j * 16 + lq);
      const unsigned u = (unsigned)((kl * 4 + hv) ^ (rm & 7));
      bf[j] = *(const bf16x8*)(AsH + rm * 128u + u * 16u);
    }
#pragma unroll
    for (int i = 0; i < 4; ++i)
#pragma unroll
      for (int j = 0; j < 4; ++j)
        acc[i][j] = __builtin_amdgcn_mfma_f32_16x16x32_bf16(
            af[i], bf[j], acc[i][j], 0, 0, 0);
  }
}

// ---------------- Fused: R7 structure + conflict-free LDS + setprio ----------------
// BM=64, BN=256 (quant-once), BK=128, 4 waves, 18 steps, grid 392 XCD-swizzled.
// LDS 80KB: As 2x8K halves + Ns 2x32K halves, all 128B rows with u^(r&7) swizzle
// (R10-proven, ~0 bank conflicts). Step: stage both Ns halves -> qfinish(win)->As
// -> qload(R+1) (15 loads cross bar) -> bar1{vmcnt(15),lgkm0} -> MFMA (setprio 1)
// -> bar2{lgkm0}.
__global__ __launch_bounds__(256, 2) void fused_gemm_kernel(
    const float* __restrict__ xpad, const __hip_bfloat16* __restrict__ wqT,
    const float* __restrict__ bias, float* __restrict__ out) {
  extern __shared__ char smem[];
  char* As0 = smem;                  // 8KB  (k 0..63 of step)
  char* As1 = smem + 8192;           // 8KB  (k 64..127)
  char* Ns0 = smem + 16384;          // 32KB
  char* Ns1 = smem + 49152;          // 32KB
  const int tid = threadIdx.x;
  const int lane = tid & 63;
  const int w = __builtin_amdgcn_readfirstlane(tid >> 6);   // 0..3

  const int bid = blockIdx.x;                    // 0..391
  const int mt = (bid & 7) * 49 + (bid >> 3);    // XCD swizzle: image d -> XCD d
  const int m0 = mt * 64;

  const int b = m0 / LD;                         // uniform (3136 % 64 == 0)
  const int l = m0 - b * LD + lane;
  const int i = l / 56;
  const int j = l - i * 56;
  const float* pb = xpad + (size_t)b * CD * PLANE;
  const int p0 = i * PITCH + j;
  const unsigned short* wsrc = (const unsigned short*)wqT;

  char* as_dst = (w < 2) ? As0 : As1;            // granule sigma = w
  const unsigned cb = (unsigned)((w & 1) * 64);
  const int lq = lane & 15, hv = lane >> 4;

  f32x4 acc[4][4] = {};
  f32x4u win[5][3];

  // prologue: win for step-0 granule (k = 32w)
  int kq = 32 * w;
  int ph = kq % 9;                               // 0,5,1,6
  qload_u(pb, p0, kq / 9, win);

  for (int R = 0; R < 18; ++R) {
    stage_ns(wsrc, R * 128, lane, w, Ns0);       // 8 async gload_lds
    stage_ns(wsrc, R * 128 + 64, lane, w, Ns1);  // 8 async gload_lds
    __builtin_amdgcn_sched_barrier(0);           // pin: stage before win-qload

    SW_FIN(ph, as_dst, cb);                      // consume win -> As half

    kq += 128;
    ph += 2; if (ph >= 9) ph -= 9;
    qload_u(pb, p0, kq / 9, win);                // 15 loads cross bar1 (clamped tail)

    // drain the 16 stage loads (older), keep the 15 win loads in flight
    asm volatile("s_waitcnt vmcnt(15) lgkmcnt(0)\n\ts_barrier" ::: "memory");
    __builtin_amdgcn_sched_barrier(0);

    __builtin_amdgcn_s_setprio(1);
    mfma_phase(As0, As1, Ns0, Ns1, acc, w, lq, hv);
    __builtin_amdgcn_s_setprio(0);

    asm volatile("s_waitcnt lgkmcnt(0)\n\ts_barrier" ::: "memory");
    __builtin_amdgcn_sched_barrier(0);
  }

  // ---- Epilogue: D row = n = w*64 + i4*16 + hv*4 + comp, col = m (coalesced) ----
#pragma unroll
  for (int i4 = 0; i4 < 4; ++i4) {
    const int nb = w * 64 + i4 * 16 + hv * 4;
    const float4 b4 = *(const float4*)&bias[nb];
#pragma unroll
    for (int j4 = 0; j4 < 4; ++j4) {
      const int m = m0 + j4 * 16 + lq;
      const int ll = m - b * LD;
      float* op = out + ((size_t)b * ND + nb) * LD + ll;
      op[0]      = acc[i4][j4].x + b4.x;
      op[LD]     = acc[i4][j4].y + b4.y;
      op[2 * LD] = acc[i4][j4].z + b4.z;
      op[3 * LD] = acc[i4][j4].w + b4.w;
    }
  }
}

extern "C" void kernel_launch(void* const* d_in, const int* in_sizes, int n_in,
                              void* d_out, int out_size, void* d_ws, size_t ws_size,
                              hipStream_t stream) {
  const float* x = (const float*)d_in[0];
  const float* wgt = (const float*)d_in[1];
  const float* bias = (const float*)d_in[2];
  float* out = (float*)d_out;

  float* xpad = (float*)d_ws;                         // 30,408,704 B
  __hip_bfloat16* wqT = (__hip_bfloat16*)((char*)d_ws + 30408704);  // 1,179,648 B

  prep_kernel<<<2048 + 576, 256, 0, stream>>>(x, xpad, wgt, wqT);
  fused_gemm_kernel<<<392, 256, 80 * 1024, stream>>>(xpad, wqT, bias, out);
}